// Round 5
// baseline (413.415 us; speedup 1.0000x reference)
//
#include <hip/hip_runtime.h>
#include <math.h>

// Problem constants (from reference): B=64, S=8192, D=64, fp32.
#define BB 64
#define SS 8192
#define DD 64

// Phase-1: 4 s-chunks x 64 batches = 256 blocks = exactly 1 block/CU.
// 3-buffer LDS pipeline (96 KiB), 2 tiles in flight via counted vmcnt.
constexpr int C1 = 4;
constexpr int CHUNK1 = SS / C1;          // 2048 s per block
constexpr int TROWS  = 64;               // s-rows per LDS tile (2 K-steps of 32)
constexpr int TILES1 = CHUNK1 / TROWS;   // 32 tiles
constexpr int NBUF   = 3;

typedef __attribute__((ext_vector_type(8))) short bf16x8;   // MFMA A/B frag (4 VGPR)
typedef __attribute__((ext_vector_type(4))) float f32x4;    // MFMA C/D frag

__device__ __forceinline__ float fmap(float x) {
    // elu(x) + 1 == (x > 0 ? x + 1 : exp(x))
    return x > 0.0f ? x + 1.0f : __expf(x);
}

// float -> bf16 round-to-nearest-even
__device__ __forceinline__ short f2bf(float x) {
    unsigned int u = __float_as_uint(x);
    u += 0x7FFFu + ((u >> 16) & 1u);
    return (short)(u >> 16);
}

// split fp32 -> (hi = bf16 truncation, lo = bf16 RNE of exact residue)
// x ~= hi + lo with |err| ~ 2^-17 |x|; products compensated via hh+hl+lh.
__device__ __forceinline__ void split8(const float* x, bf16x8& hi, bf16x8& lo) {
    #pragma unroll
    for (int i = 0; i < 8; ++i) {
        unsigned int u = __float_as_uint(x[i]);
        hi[i] = (short)(u >> 16);                          // truncate = exact bf16 head
        float l = x[i] - __uint_as_float(u & 0xFFFF0000u); // exact residue in fp32
        lo[i] = f2bf(l);
    }
}

__device__ __forceinline__ void gload_lds16(const float* gsrc, float* ldst) {
    __builtin_amdgcn_global_load_lds(
        (const __attribute__((address_space(1))) unsigned int*)gsrc,
        (__attribute__((address_space(3))) unsigned int*)ldst,
        16, 0, 0);
}

// -------------------------------------------------------------------------
// Phase 1 (MFMA): kvT[b][e][d] = sum_s v[b][s][e] * fmap(k[b][s][d])
//                 ksum[b][d]   = sum_s fmap(k[b][s][d])
// A = v^T (m=e, k=s), B = fmap(k) (k=s, n=d)  ->  D[e][d] = kvT directly.
// Both operands hi/lo-split (3 MFMA terms) for near-fp32 accuracy.
// Pipeline (T3/T4): 3 LDS buffers, 2 tiles (16 gload_lds/wave = 16 KB) in
// flight; per-tile wait is s_waitcnt vmcnt(8) (never 0 in the loop) + raw
// s_barrier. Barrier precedes the t+2 issue, making buffer rotation WAR-safe.
// 16B-chunk XOR swizzle (ch ^= ((s>>3)&1)<<2) pre-applied to GLOBAL source
// so stride-256B fragment gathers are <=2-way bank aliased (free).
// Wave split: step = w&1 owns K-rows step*32..+32; dh = w>>1 owns output
// columns dh*32..+32. 96 wave-MFMA/tile = exact work, no redundancy.
// -------------------------------------------------------------------------
__global__ __launch_bounds__(256) void phase1_kernel(
    const float* __restrict__ k,
    const float* __restrict__ v,
    float* __restrict__ kvT_ws,   // [B][D(e)][D(d)], pre-zeroed
    float* __restrict__ ksum_ws)  // [B][D],          pre-zeroed
{
    __shared__ float Ks[NBUF][TROWS * 64];   // 3 x 16 KiB
    __shared__ float Vs[NBUF][TROWS * 64];   // 3 x 16 KiB   (total 96 KiB)

    const int t    = threadIdx.x;
    const int lane = t & 63;
    const int w    = t >> 6;          // wave 0..3
    const int g    = lane >> 4;       // k-group 0..3
    const int c    = lane & 15;       // frag row/col
    const int b    = blockIdx.y;
    const int step = w & 1;           // which K=32 slab of the tile
    const int dh   = w >> 1;          // which 32-column output half

    const size_t base = (size_t)b * SS * DD + (size_t)blockIdx.x * CHUNK1 * DD;
    const float* kb = k + base;
    const float* vb = v + base;

    // stage one 64x64 fp32 tile of each matrix (exactly 8 gload_lds per wave)
    auto issue_tile = [&](int tt, int buf) {
        const float* kt = kb + tt * (TROWS * 64);
        const float* vt = vb + tt * (TROWS * 64);
        #pragma unroll
        for (int i = 0; i < 4; ++i) {
            const int Lidx = i * 256 + t;               // 16B-chunk linear index 0..1023
            const int s    = Lidx >> 4;                 // tile row
            const int p    = Lidx & 15;                 // stored chunk pos
            const int gch  = p ^ (((s >> 3) & 1) << 2); // global chunk (XOR involution)
            const int goff = s * 64 + gch * 4;          // float offset in tile
            const int loff = (i * 256 + w * 64) * 4;    // wave-uniform LDS float offset
            gload_lds16(kt + goff, &Ks[buf][loff]);
            gload_lds16(vt + goff, &Vs[buf][loff]);
        }
    };

    f32x4 acc[4][2] = {};   // [et][j] -> D rows e=et*16+4g+r, cols d=(dh*2+j)*16+c
    float ksa[2] = {};

    const int srow = step * 32 + g * 8;    // lane's first k-row in the tile
    const int sw   = (g & 1) << 2;         // swizzle key ((s>>3)&1 == g&1 here)

    auto compute_tile = [&](int buf) {
        const float* Kc = Ks[buf];
        const float* Vc = Vs[buf];
        // ---- A-frags from V (no fmap), hi/lo split; all 4 e-tiles ----
        bf16x8 Ah[4], Al[4];
        #pragma unroll
        for (int et = 0; et < 4; ++et) {
            const int dc   = et * 16 + c;      // e-coordinate
            const int bidx = srow * 64 + (((dc >> 2) ^ sw) << 2) + (dc & 3);
            float x[8];
            #pragma unroll
            for (int i = 0; i < 8; ++i) x[i] = Vc[bidx + i * 64];
            split8(x, Ah[et], Al[et]);
        }
        // ---- B-frags from K (fmap'd), this wave's 2 d-tiles; MFMA; ksum ----
        #pragma unroll
        for (int j = 0; j < 2; ++j) {
            const int dc   = (dh * 2 + j) * 16 + c;    // d-coordinate
            const int bidx = srow * 64 + (((dc >> 2) ^ sw) << 2) + (dc & 3);
            float y[8];
            #pragma unroll
            for (int i = 0; i < 8; ++i) y[i] = fmap(Kc[bidx + i * 64]);
            ksa[j] += ((y[0] + y[1]) + (y[2] + y[3])) + ((y[4] + y[5]) + (y[6] + y[7]));
            bf16x8 Bh, Bl;
            split8(y, Bh, Bl);
            #pragma unroll
            for (int et = 0; et < 4; ++et) {
                acc[et][j] = __builtin_amdgcn_mfma_f32_16x16x32_bf16(Ah[et], Bh, acc[et][j], 0, 0, 0);
                acc[et][j] = __builtin_amdgcn_mfma_f32_16x16x32_bf16(Ah[et], Bl, acc[et][j], 0, 0, 0);
                acc[et][j] = __builtin_amdgcn_mfma_f32_16x16x32_bf16(Al[et], Bh, acc[et][j], 0, 0, 0);
            }
        }
    };

    // ---- prologue: 2 tiles in flight ----
    issue_tile(0, 0);
    issue_tile(1, 1);

    // ---- main loop: wait-oldest(vmcnt 8) -> barrier -> issue t+2 -> compute t ----
    for (int tt = 0; tt < TILES1 - 1; ++tt) {
        asm volatile("s_waitcnt vmcnt(8)" ::: "memory");   // tile tt landed (own 8 oldest)
        __builtin_amdgcn_sched_barrier(0);
        __builtin_amdgcn_s_barrier();                      // all waves' tt landed; prev readers done
        __builtin_amdgcn_sched_barrier(0);
        if (tt + 2 < TILES1) issue_tile(tt + 2, (tt + 2) % NBUF);
        compute_tile(tt % NBUF);
    }
    // ---- peeled last tile ----
    asm volatile("s_waitcnt vmcnt(0)" ::: "memory");
    __builtin_amdgcn_sched_barrier(0);
    __builtin_amdgcn_s_barrier();
    __builtin_amdgcn_sched_barrier(0);
    compute_tile((TILES1 - 1) % NBUF);

    __syncthreads();   // all waves done with LDS tiles; safe to reuse as scratch

    // ---- ksum: reduce over the 4 k-groups (rows), one atomic per column ----
    #pragma unroll
    for (int j = 0; j < 2; ++j) {
        float s = ksa[j];
        s += __shfl_xor(s, 16, 64);
        s += __shfl_xor(s, 32, 64);
        ksa[j] = s;
    }
    if (lane < 16) {
        #pragma unroll
        for (int j = 0; j < 2; ++j)
            atomicAdd(ksum_ws + b * DD + (dh * 2 + j) * 16 + lane, ksa[j]);
    }

    // ---- cross-wave pair reduction: wave(step1,dh) -> wave(step0,dh) ----
    // odd waves dump acc into Ks[0] scratch (2048 floats each), even waves add.
    {
        float* scr = &Ks[0][0] + dh * 2048;
        if (step == 1) {
            #pragma unroll
            for (int et = 0; et < 4; ++et)
                #pragma unroll
                for (int j = 0; j < 2; ++j)
                    #pragma unroll
                    for (int r = 0; r < 4; ++r)
                        scr[((et * 2 + j) * 4 + r) * 64 + lane] = acc[et][j][r];
        }
    }
    __syncthreads();
    if (step == 0) {
        const float* scr = &Ks[0][0] + dh * 2048;
        float* cscr = &Vs[0][0];   // commit scratch arranged [e][d], 64x64
        #pragma unroll
        for (int et = 0; et < 4; ++et)
            #pragma unroll
            for (int j = 0; j < 2; ++j)
                #pragma unroll
                for (int r = 0; r < 4; ++r) {
                    const float s = acc[et][j][r] + scr[((et * 2 + j) * 4 + r) * 64 + lane];
                    const int e = et * 16 + 4 * g + r;
                    const int d = (dh * 2 + j) * 16 + c;
                    cscr[e * 64 + d] = s;
                }
    }
    __syncthreads();
    // ---- coalesced atomic commit from Vs[0] ----
    float* kvb = kvT_ws + (size_t)b * DD * DD;
    const float* cscr = &Vs[0][0];
    #pragma unroll
    for (int jj = 0; jj < 16; ++jj) {
        const int i = jj * 256 + t;   // lane-consecutive -> coalesced
        atomicAdd(kvb + i, cscr[i]);
    }
}

// -------------------------------------------------------------------------
// Phase 2: o[b][s][e] = (sum_d qf[s][d] * kv[d][e]) / max(sum_d qf[s][d]*ksum[d], 1e-4)
// MFMA 16x16x32 bf16. No LDS, no barriers. Software-pipelined q loads:
// tile tt+1's four float4 are issued before computing tile tt.
// grid (16, B), block 256: wave (blockIdx.x*4+w) owns 128 s-rows (8 16-row tiles).
// -------------------------------------------------------------------------
__global__ __launch_bounds__(256) void phase2_kernel(
    const float* __restrict__ q,
    const float* __restrict__ kvT_ws,
    const float* __restrict__ ksum_ws,
    float* __restrict__ o)
{
    const int t    = threadIdx.x;
    const int lane = t & 63;
    const int w    = t >> 6;
    const int b    = blockIdx.y;
    const int wid  = blockIdx.x * 4 + w;   // 0..63
    const int g    = lane >> 4;            // k-group 0..3
    const int c    = lane & 15;            // A row / B col / D col

    // ---- preload kv B-fragments: B[k=d][n=e] from kvT[e][d] (contiguous d) ----
    const float* kvb = kvT_ws + (size_t)b * DD * DD;
    bf16x8 Bfrag[4][2];
    #pragma unroll
    for (int et = 0; et < 4; ++et) {
        #pragma unroll
        for (int dk = 0; dk < 2; ++dk) {
            const float* p = kvb + (et * 16 + c) * DD + dk * 32 + g * 8;
            float4 lo = *(const float4*)p;
            float4 hi = *(const float4*)(p + 4);
            bf16x8 f;
            f[0] = f2bf(lo.x); f[1] = f2bf(lo.y); f[2] = f2bf(lo.z); f[3] = f2bf(lo.w);
            f[4] = f2bf(hi.x); f[5] = f2bf(hi.y); f[6] = f2bf(hi.z); f[7] = f2bf(hi.w);
            Bfrag[et][dk] = f;
        }
    }
    // ksum (fp32) at the same per-lane d-indices as the A-fragment
    float ksr[16];
    #pragma unroll
    for (int dk = 0; dk < 2; ++dk) {
        const float* p = ksum_ws + b * DD + dk * 32 + g * 8;
        float4 lo = *(const float4*)p;
        float4 hi = *(const float4*)(p + 4);
        ksr[dk*8+0] = lo.x; ksr[dk*8+1] = lo.y; ksr[dk*8+2] = lo.z; ksr[dk*8+3] = lo.w;
        ksr[dk*8+4] = hi.x; ksr[dk*8+5] = hi.y; ksr[dk*8+6] = hi.z; ksr[dk*8+7] = hi.w;
    }

    const float* qb = q + (size_t)b * SS * DD;
    float*       ob = o + (size_t)b * SS * DD;

    // prefetch registers for the software pipeline
    const float* qrow = qb + (size_t)(wid * 128 + c) * DD;
    float4 p0 = *(const float4*)(qrow + g * 8);
    float4 p1 = *(const float4*)(qrow + g * 8 + 4);
    float4 p2 = *(const float4*)(qrow + 32 + g * 8);
    float4 p3 = *(const float4*)(qrow + 32 + g * 8 + 4);

    #pragma unroll 1
    for (int tt = 0; tt < 8; ++tt) {
        const int s0 = wid * 128 + tt * 16;
        float4 c0 = p0, c1 = p1, c2 = p2, c3 = p3;
        if (tt < 7) {   // issue next tile's loads before computing current
            const float* qn = qb + (size_t)(s0 + 16 + c) * DD;
            p0 = *(const float4*)(qn + g * 8);
            p1 = *(const float4*)(qn + g * 8 + 4);
            p2 = *(const float4*)(qn + 32 + g * 8);
            p3 = *(const float4*)(qn + 32 + g * 8 + 4);
        }
        float qf[16];
        qf[0]  = fmap(c0.x); qf[1]  = fmap(c0.y); qf[2]  = fmap(c0.z); qf[3]  = fmap(c0.w);
        qf[4]  = fmap(c1.x); qf[5]  = fmap(c1.y); qf[6]  = fmap(c1.z); qf[7]  = fmap(c1.w);
        qf[8]  = fmap(c2.x); qf[9]  = fmap(c2.y); qf[10] = fmap(c2.z); qf[11] = fmap(c2.w);
        qf[12] = fmap(c3.x); qf[13] = fmap(c3.y); qf[14] = fmap(c3.z); qf[15] = fmap(c3.w);

        // ---- denominator in fp32: partial dot + reduce over the 4 k-groups ----
        float dn = 0.0f;
        #pragma unroll
        for (int i = 0; i < 16; ++i) dn += qf[i] * ksr[i];
        dn += __shfl_xor(dn, 16, 64);
        dn += __shfl_xor(dn, 32, 64);   // dn = deno for row (s0 + c), on all lanes

        // ---- pack A-fragments (bf16) ----
        bf16x8 A0, A1;
        #pragma unroll
        for (int i = 0; i < 8; ++i) { A0[i] = f2bf(qf[i]); A1[i] = f2bf(qf[8+i]); }

        // ---- MFMA: 4 e-tiles x 2 k-chunks ----
        f32x4 acc0 = {0.f,0.f,0.f,0.f}, acc1 = {0.f,0.f,0.f,0.f};
        f32x4 acc2 = {0.f,0.f,0.f,0.f}, acc3 = {0.f,0.f,0.f,0.f};
        acc0 = __builtin_amdgcn_mfma_f32_16x16x32_bf16(A0, Bfrag[0][0], acc0, 0, 0, 0);
        acc0 = __builtin_amdgcn_mfma_f32_16x16x32_bf16(A1, Bfrag[0][1], acc0, 0, 0, 0);
        acc1 = __builtin_amdgcn_mfma_f32_16x16x32_bf16(A0, Bfrag[1][0], acc1, 0, 0, 0);
        acc1 = __builtin_amdgcn_mfma_f32_16x16x32_bf16(A1, Bfrag[1][1], acc1, 0, 0, 0);
        acc2 = __builtin_amdgcn_mfma_f32_16x16x32_bf16(A0, Bfrag[2][0], acc2, 0, 0, 0);
        acc2 = __builtin_amdgcn_mfma_f32_16x16x32_bf16(A1, Bfrag[2][1], acc2, 0, 0, 0);
        acc3 = __builtin_amdgcn_mfma_f32_16x16x32_bf16(A0, Bfrag[3][0], acc3, 0, 0, 0);
        acc3 = __builtin_amdgcn_mfma_f32_16x16x32_bf16(A1, Bfrag[3][1], acc3, 0, 0, 0);

        // ---- epilogue: D[row=4g+r][col=c]; deno for row 4g+r from lane (4g+r) ----
        #pragma unroll
        for (int r = 0; r < 4; ++r) {
            float dr  = __shfl(dn, (g << 2) + r, 64);
            float inv = 1.0f / fmaxf(dr, 1e-4f);
            float* op = ob + (size_t)(s0 + (g << 2) + r) * DD + c;
            op[0]  = acc0[r] * inv;
            op[16] = acc1[r] * inv;
            op[32] = acc2[r] * inv;
            op[48] = acc3[r] * inv;
        }
    }
}

extern "C" void kernel_launch(void* const* d_in, const int* in_sizes, int n_in,
                              void* d_out, int out_size, void* d_ws, size_t ws_size,
                              hipStream_t stream) {
    const float* q = (const float*)d_in[0];
    const float* k = (const float*)d_in[1];
    const float* v = (const float*)d_in[2];
    float* o = (float*)d_out;

    float* kvT_ws  = (float*)d_ws;                       // B*D*D floats, [b][e][d]
    float* ksum_ws = kvT_ws + (size_t)BB * DD * DD;      // B*D floats
    const size_t ws_bytes = ((size_t)BB * DD * DD + (size_t)BB * DD) * sizeof(float);

    // Workspace is re-poisoned before every timed launch -> zero it.
    hipMemsetAsync(d_ws, 0, ws_bytes, stream);

    dim3 g1(C1, BB), g2(16, BB), blk(256);
    phase1_kernel<<<g1, blk, 0, stream>>>(k, v, kvT_ws, ksum_ws);
    phase2_kernel<<<g2, blk, 0, stream>>>(q, kvT_ws, ksum_ws, o);
}